// Round 12
// baseline (463.577 us; speedup 1.0000x reference)
//
#include <hip/hip_runtime.h>
#include <math.h>

#define BB 16
#define NN 577
#define CC 768
#define HH 12
#define HD 64
#define MM (BB*NN)      // 9232
#define MPAD 9344       // 73*128
#define LEFT 404
#define NPAD 608        // padded token count (19 chunks of 32)
#define NQT 10          // ceil(577/64) q-tiles of 64

typedef __attribute__((ext_vector_type(8))) short short8v;   // 8 bf16
typedef __attribute__((ext_vector_type(4))) float f32x4;

__device__ __forceinline__ unsigned short f2bf(float f) {
    union { float f; unsigned int u; } v; v.f = f;
    unsigned int r = v.u + 0x7fffu + ((v.u >> 16) & 1u);   // RNE
    return (unsigned short)(r >> 16);
}

// async global->LDS 16B per lane; LDS dst must be wave-uniform base (+lane*16)
#define GLDS16(gp, lp)                                                        \
    __builtin_amdgcn_global_load_lds(                                         \
        (const __attribute__((address_space(1))) void*)(gp),                  \
        (__attribute__((address_space(3))) void*)(lp), 16, 0, 0)

// ---------------------------------------------------------------------------
// fp32 K-GEMM v6: 128x128 tile, 8x8 conflict-free micro (4+4 offsets),
// BK=64 single-buffer LDS (24 barriers/block vs 96) — barrier/drain
// amortization at the grid-pinned 438-block occupancy.
// Per-output ascending-k fmaf chain UNCHANGED -> kb bit-exact (lottery draw).
// ---------------------------------------------------------------------------
__global__ __launch_bounds__(256) void k_gemm_fp32(const float* __restrict__ X,
                                                   const float* __restrict__ W,
                                                   float* __restrict__ kb,
                                                   unsigned short* __restrict__ kbh)
{
    __shared__ float Xs[64][128];    // 32 KB
    __shared__ float Ws[64][128];    // 32 KB
    const int t  = threadIdx.x;
    const int tx = t & 15, ty = t >> 4;
    const int m0 = blockIdx.x * 128;
    const int n0 = 768 + blockIdx.y * 128;     // K columns of W
    const int sm   = t & 127;                  // staged row (m for X, n for W)
    const int half = t >> 7;                   // k-half: 0 -> k[0,32), 1 -> k[32,64)

    float acc[8][8];
    #pragma unroll
    for (int i = 0; i < 8; ++i)
        #pragma unroll
        for (int j = 0; j < 8; ++j) acc[i][j] = 0.f;

    const int gm = m0 + sm;
    const float* px = X + (size_t)gm * CC + half * 32;
    const float* pw = W + (size_t)(n0 + sm) * CC + half * 32;

    for (int kk = 0; kk < CC; kk += 64) {
        {   // stage 64-deep K-tile (8 float4 per thread per operand)
            float4 xa[8], wb[8];
            #pragma unroll
            for (int q = 0; q < 8; ++q) {
                xa[q] = make_float4(0.f, 0.f, 0.f, 0.f);
                if (gm < MM) xa[q] = *(const float4*)(px + kk + q*4);
                wb[q] = *(const float4*)(pw + kk + q*4);
            }
            #pragma unroll
            for (int q = 0; q < 8; ++q) {
                const int ks = half*32 + q*4;
                Xs[ks+0][sm] = xa[q].x; Xs[ks+1][sm] = xa[q].y;
                Xs[ks+2][sm] = xa[q].z; Xs[ks+3][sm] = xa[q].w;
                Ws[ks+0][sm] = wb[q].x; Ws[ks+1][sm] = wb[q].y;
                Ws[ks+2][sm] = wb[q].z; Ws[ks+3][sm] = wb[q].w;
            }
        }
        __syncthreads();
        #pragma unroll
        for (int k = 0; k < 64; ++k) {
            float a[8], bv[8];
            *(float4*)&a[0]  = *(const float4*)&Xs[k][ty*4];        // broadcast groups
            *(float4*)&a[4]  = *(const float4*)&Xs[k][64 + ty*4];
            *(float4*)&bv[0] = *(const float4*)&Ws[k][tx*4];        // 16B stride = 2-way (free)
            *(float4*)&bv[4] = *(const float4*)&Ws[k][64 + tx*4];
            #pragma unroll
            for (int i = 0; i < 8; ++i)
                #pragma unroll
                for (int j = 0; j < 8; ++j)
                    acc[i][j] = fmaf(a[i], bv[j], acc[i][j]);
        }
        __syncthreads();
    }
    #pragma unroll
    for (int i = 0; i < 8; ++i) {
        const int mrow = m0 + ((i < 4) ? (ty*4 + i) : (64 + ty*4 + i - 4));
        if (mrow >= MM) continue;
        const int b_ = mrow / NN;
        const int n_ = mrow - b_ * NN;
        #pragma unroll
        for (int j = 0; j < 8; ++j) {
            const int col = (n0 - 768) + ((j < 4) ? (tx*4 + j) : (64 + tx*4 + j - 4));
            const int h = col >> 6, d = col & 63;
            const float a = acc[i][j];
            kb [(((size_t)b_ * HH + h) * NN   + n_) * HD + d] = a;
            kbh[(((size_t)b_ * HH + h) * NPAD + n_) * HD + d] = f2bf(a);
        }
    }
}

// ---------------------------------------------------------------------------
// Exact fp32 q_cls (row 0 per (b,h)) — ascending-k fmaf chain [validated]
// ---------------------------------------------------------------------------
__global__ __launch_bounds__(256) void qcls_kernel(const float* __restrict__ X,
                                                   const float* __restrict__ W,
                                                   float* __restrict__ qcls)
{
    const int b = blockIdx.x;
    const int col = blockIdx.y * 256 + threadIdx.x;   // 0..767
    const float* xr = X + (size_t)b * NN * CC;        // CLS row
    const float* wr = W + (size_t)col * CC;
    float acc = 0.f;
    for (int k = 0; k < CC; ++k) acc = fmaf(xr[k], wr[k], acc);
    qcls[(size_t)b * CC + col] = acc;
}

// ---------------------------------------------------------------------------
// fp32 -> bf16 conversions (x, qkv_w, proj_w) in one launch [R5-validated]
// ---------------------------------------------------------------------------
#define N4X 1772544   // 9232*768/4
#define N4W 442368    // 2304*768/4
#define N4P 147456    // 768*768/4
__global__ __launch_bounds__(256) void convert3(const float* __restrict__ x,
                                                const float* __restrict__ wq,
                                                const float* __restrict__ wp,
                                                unsigned short* __restrict__ xb,
                                                unsigned short* __restrict__ wqb,
                                                unsigned short* __restrict__ wpb)
{
    int g = blockIdx.x * 256 + threadIdx.x;
    const float* src; unsigned short* dst;
    if (g < N4X)            { src = x;  dst = xb;  }
    else if (g < N4X + N4W) { g -= N4X; src = wq; dst = wqb; }
    else                    { g -= (N4X + N4W); src = wp; dst = wpb; }
    const float4 v = ((const float4*)src)[g];
    ushort4 o;
    o.x = f2bf(v.x); o.y = f2bf(v.y); o.z = f2bf(v.z); o.w = f2bf(v.w);
    ((ushort4*)dst)[g] = o;
}

// ---------------------------------------------------------------------------
// bf16 MFMA GEMM for Q and V — gload_lds double-buffered [R11-validated]
// ---------------------------------------------------------------------------
__global__ __launch_bounds__(256) void qv_mfma(const unsigned short* __restrict__ xbh,
                                               const unsigned short* __restrict__ wqkv,
                                               unsigned short* __restrict__ qbh,
                                               unsigned short* __restrict__ Vt)
{
    __shared__ unsigned short As[2][4096];   // [buf][128 rows x 32 k] bf16, 8 KB each
    __shared__ unsigned short Bs[2][4096];
    const int t = threadIdx.x;
    const int w = t >> 6, l = t & 63;
    const int l15 = l & 15, lk = l >> 4;
    const int wm = w >> 1, wn = w & 1;
    const int m0 = blockIdx.x * 128;
    const int isV = blockIdx.y >= 6;
    const int nlocal0 = (isV ? (blockIdx.y - 6) : blockIdx.y) * 128;
    const int wrow0 = (isV ? 1536 : 0) + nlocal0;
    const int r0 = t >> 2, segp = t & 3;

    f32x4 acc[4][4];
    #pragma unroll
    for (int i = 0; i < 4; ++i)
        #pragma unroll
        for (int j = 0; j < 4; ++j) acc[i][j] = (f32x4){0.f,0.f,0.f,0.f};

    const unsigned short* ga = xbh  + (size_t)(m0 + r0) * CC + segp * 8;
    const unsigned short* gb = wqkv + (size_t)(wrow0 + r0) * CC + segp * 8;
    const int wbase = w * 512;               // per-wave LDS base (shorts)

    #define QV_STAGE(bb, kk)                                                  \
        do {                                                                  \
            GLDS16(ga + (kk),                   &As[bb][wbase]);              \
            GLDS16(ga + (kk) + (size_t)64 * CC, &As[bb][2048 + wbase]);       \
            GLDS16(gb + (kk),                   &Bs[bb][wbase]);              \
            GLDS16(gb + (kk) + (size_t)64 * CC, &Bs[bb][2048 + wbase]);       \
        } while (0)

    QV_STAGE(0, 0);
    __syncthreads();                          // implicit vmcnt(0) drain
    int cur = 0;
    for (int kk = 0; kk < CC; kk += 32) {
        if (kk + 32 < CC) QV_STAGE(cur ^ 1, kk + 32);   // async prefetch
        short8v fa[4], fb[4];
        #pragma unroll
        for (int i = 0; i < 4; ++i) fa[i] = *(const short8v*)&As[cur][(wm*64 + i*16 + l15)*32 + lk*8];
        #pragma unroll
        for (int j = 0; j < 4; ++j) fb[j] = *(const short8v*)&Bs[cur][(wn*64 + j*16 + l15)*32 + lk*8];
        #pragma unroll
        for (int i = 0; i < 4; ++i)
            #pragma unroll
            for (int j = 0; j < 4; ++j)
                acc[i][j] = __builtin_amdgcn_mfma_f32_16x16x32_bf16(fa[i], fb[j], acc[i][j], 0, 0, 0);
        __syncthreads();                      // drains prefetch + read fence
        cur ^= 1;
    }
    #undef QV_STAGE

    const int nb = nlocal0 + wn*64 + l15;
    #pragma unroll
    for (int i = 0; i < 4; ++i) {
        #pragma unroll
        for (int r = 0; r < 4; ++r) {
            const int m = m0 + wm*64 + i*16 + 4*lk + r;
            if (m >= MM) continue;
            const int b_ = m / NN, tok = m - b_ * NN;
            #pragma unroll
            for (int j = 0; j < 4; ++j) {
                const int nl = nb + j*16;
                const int h = nl >> 6, d = nl & 63;
                const unsigned short v = f2bf(acc[i][j][r]);
                if (isV) Vt [(((size_t)b_*HH + h)*HD + d)*NPAD + tok] = v;
                else     qbh[(((size_t)b_*HH + h)*NPAD + tok)*HD + d] = v;
            }
        }
    }
}

// ---------------------------------------------------------------------------
// proj GEMM — gload_lds double-buffered [R11-validated]; out fp32 + bias.
// ---------------------------------------------------------------------------
__global__ __launch_bounds__(256) void proj_mfma(const unsigned short* __restrict__ aobh,
                                                 const unsigned short* __restrict__ wpb,
                                                 const float* __restrict__ bias,
                                                 float* __restrict__ outp)
{
    __shared__ unsigned short As[2][4096];
    __shared__ unsigned short Bs[2][4096];
    const int t = threadIdx.x;
    const int w = t >> 6, l = t & 63;
    const int l15 = l & 15, lk = l >> 4;
    const int wm = w >> 1, wn = w & 1;
    const int m0 = blockIdx.x * 128;
    const int n0 = blockIdx.y * 128;
    const int r0 = t >> 2, segp = t & 3;

    f32x4 acc[4][4];
    #pragma unroll
    for (int i = 0; i < 4; ++i)
        #pragma unroll
        for (int j = 0; j < 4; ++j) acc[i][j] = (f32x4){0.f,0.f,0.f,0.f};

    const unsigned short* ga = aobh + (size_t)(m0 + r0) * CC + segp * 8;
    const unsigned short* gb = wpb  + (size_t)(n0 + r0) * CC + segp * 8;
    const int wbase = w * 512;

    #define PJ_STAGE(bb, kk)                                                  \
        do {                                                                  \
            GLDS16(ga + (kk),                   &As[bb][wbase]);              \
            GLDS16(ga + (kk) + (size_t)64 * CC, &As[bb][2048 + wbase]);       \
            GLDS16(gb + (kk),                   &Bs[bb][wbase]);              \
            GLDS16(gb + (kk) + (size_t)64 * CC, &Bs[bb][2048 + wbase]);       \
        } while (0)

    PJ_STAGE(0, 0);
    __syncthreads();
    int cur = 0;
    for (int kk = 0; kk < CC; kk += 32) {
        if (kk + 32 < CC) PJ_STAGE(cur ^ 1, kk + 32);
        short8v fa[4], fb[4];
        #pragma unroll
        for (int i = 0; i < 4; ++i) fa[i] = *(const short8v*)&As[cur][(wm*64 + i*16 + l15)*32 + lk*8];
        #pragma unroll
        for (int j = 0; j < 4; ++j) fb[j] = *(const short8v*)&Bs[cur][(wn*64 + j*16 + l15)*32 + lk*8];
        #pragma unroll
        for (int i = 0; i < 4; ++i)
            #pragma unroll
            for (int j = 0; j < 4; ++j)
                acc[i][j] = __builtin_amdgcn_mfma_f32_16x16x32_bf16(fa[i], fb[j], acc[i][j], 0, 0, 0);
        __syncthreads();
        cur ^= 1;
    }
    #undef PJ_STAGE

    const int nb = n0 + wn*64 + l15;
    #pragma unroll
    for (int i = 0; i < 4; ++i) {
        #pragma unroll
        for (int r = 0; r < 4; ++r) {
            const int m = m0 + wm*64 + i*16 + 4*lk + r;
            if (m >= MM) continue;
            #pragma unroll
            for (int j = 0; j < 4; ++j) {
                const int n = nb + j*16;
                outp[(size_t)m * CC + n] = acc[i][j][r] + bias[n];
            }
        }
    }
}

// ---------------------------------------------------------------------------
// MFMA flash attention [validated R5/R10]: bf16 in (qbh/kbh/Vt), bf16 out
// ---------------------------------------------------------------------------
__global__ __launch_bounds__(256) void attn_mfma(const unsigned short* __restrict__ qbh,
                                                 const unsigned short* __restrict__ kbh,
                                                 const unsigned short* __restrict__ Vt,
                                                 unsigned short* __restrict__ aobh)
{
    __shared__ __align__(16) unsigned short plds[4][16][32];
    const int bid = blockIdx.x;
    const int bh  = bid / NQT;
    const int qt  = bid - bh * NQT;
    const int b   = bh / HH, h = bh - b * HH;
    const int t   = threadIdx.x;
    const int w   = t >> 6, l = t & 63;
    const int l15 = l & 15, lg = l >> 4;

    short8v aq0, aq1;
    {
        int qrow = qt*64 + w*16 + l15; if (qrow > 576) qrow = 576;
        const unsigned short* qp = qbh + ((size_t)bh * NPAD + qrow) * HD + lg*8;
        aq0 = *(const short8v*)(qp);
        aq1 = *(const short8v*)(qp + 32);
    }

    f32x4 O0 = {0.f,0.f,0.f,0.f}, O1 = O0, O2 = O0, O3 = O0;
    float mr[4] = {-1e30f,-1e30f,-1e30f,-1e30f};
    float lr[4] = {0.f,0.f,0.f,0.f};

    const unsigned short* kwb = kbh + (size_t)bh * NPAD * HD + (size_t)l15 * HD + lg*8;
    const unsigned short* vwb = Vt  + (size_t)bh * HD * NPAD + (size_t)l15 * NPAD + lg*8;

    for (int c = 0; c < 19; ++c) {
        const int n0 = c * 32;
        const unsigned short* kp = kwb + (size_t)n0 * HD;
        short8v bk00 = *(const short8v*)(kp);
        short8v bk01 = *(const short8v*)(kp + 32);
        short8v bk10 = *(const short8v*)(kp + 16*HD);
        short8v bk11 = *(const short8v*)(kp + 16*HD + 32);
        f32x4 s0 = {0.f,0.f,0.f,0.f}, s1 = {0.f,0.f,0.f,0.f};
        s0 = __builtin_amdgcn_mfma_f32_16x16x32_bf16(aq0, bk00, s0, 0, 0, 0);
        s0 = __builtin_amdgcn_mfma_f32_16x16x32_bf16(aq1, bk01, s0, 0, 0, 0);
        s1 = __builtin_amdgcn_mfma_f32_16x16x32_bf16(aq0, bk10, s1, 0, 0, 0);
        s1 = __builtin_amdgcn_mfma_f32_16x16x32_bf16(aq1, bk11, s1, 0, 0, 0);

        const int nc0 = n0 + l15;
        float p0[4], p1[4], al[4];
        #pragma unroll
        for (int r = 0; r < 4; ++r) {
            float a0 = (nc0      <= 576) ? s0[r] * 0.125f : -1e30f;
            float a1 = (nc0 + 16 <= 576) ? s1[r] * 0.125f : -1e30f;
            float tm = fmaxf(a0, a1);
            tm = fmaxf(tm, __shfl_xor(tm, 1, 64));
            tm = fmaxf(tm, __shfl_xor(tm, 2, 64));
            tm = fmaxf(tm, __shfl_xor(tm, 4, 64));
            tm = fmaxf(tm, __shfl_xor(tm, 8, 64));
            const float mn = fmaxf(mr[r], tm);
            al[r] = __expf(mr[r] - mn);
            mr[r] = mn;
            p0[r] = __expf(a0 - mn);
            p1[r] = __expf(a1 - mn);
            float ps = p0[r] + p1[r];
            ps += __shfl_xor(ps, 1, 64);
            ps += __shfl_xor(ps, 2, 64);
            ps += __shfl_xor(ps, 4, 64);
            ps += __shfl_xor(ps, 8, 64);
            lr[r] = lr[r] * al[r] + ps;
        }
        #pragma unroll
        for (int r = 0; r < 4; ++r) {
            O0[r] *= al[r]; O1[r] *= al[r]; O2[r] *= al[r]; O3[r] *= al[r];
        }
        #pragma unroll
        for (int r = 0; r < 4; ++r) {
            plds[w][lg*4 + r][l15]      = f2bf(p0[r]);
            plds[w][lg*4 + r][16 + l15] = f2bf(p1[r]);
        }
        asm volatile("s_waitcnt lgkmcnt(0)" ::: "memory");
        short8v pa = *(const short8v*)&plds[w][l15][lg*8];
        const unsigned short* vp = vwb + n0;
        short8v v0 = *(const short8v*)(vp);
        short8v v1 = *(const short8v*)(vp + 16*NPAD);
        short8v v2 = *(const short8v*)(vp + 32*NPAD);
        short8v v3 = *(const short8v*)(vp + 48*NPAD);
        O0 = __builtin_amdgcn_mfma_f32_16x16x32_bf16(pa, v0, O0, 0, 0, 0);
        O1 = __builtin_amdgcn_mfma_f32_16x16x32_bf16(pa, v1, O1, 0, 0, 0);
        O2 = __builtin_amdgcn_mfma_f32_16x16x32_bf16(pa, v2, O2, 0, 0, 0);
        O3 = __builtin_amdgcn_mfma_f32_16x16x32_bf16(pa, v3, O3, 0, 0, 0);
    }

    #pragma unroll
    for (int r = 0; r < 4; ++r) {
        const float inv = 1.f / lr[r];
        const int row = qt*64 + w*16 + lg*4 + r;
        if (row <= 576) {
            unsigned short* op = aobh + ((size_t)b * NN + row) * CC + h*HD + l15;
            op[0]  = f2bf(O0[r] * inv);
            op[16] = f2bf(O1[r] * inv);
            op[32] = f2bf(O2[r] * inv);
            op[48] = f2bf(O3[r] * inv);
        }
    }
}

// ---------------------------------------------------------------------------
// CLS path — bit-identical math to the passing R3..R11 draw [R9 split]
// ---------------------------------------------------------------------------
__global__ __launch_bounds__(256) void cls_logits(const float* __restrict__ qcls,
                                                  const float* __restrict__ kb,
                                                  float* __restrict__ P)
{
    const int bh = blockIdx.x;
    const int t = threadIdx.x;
    __shared__ float q[64];
    if (t < 64) q[t] = qcls[(size_t)bh * 64 + t];
    __syncthreads();
    const int n = blockIdx.y * 193 + t;
    if (t < 193 && n < NN) {
        const float* kr = kb + ((size_t)bh * NN + n) * HD;
        float acc = 0.f;
        #pragma unroll
        for (int d = 0; d < 64; ++d) acc = fmaf(q[d], kr[d], acc);
        P[(size_t)bh * NN + n] = acc * 0.125f;
    }
}

__global__ __launch_bounds__(256) void cls_softmax(float* __restrict__ P)
{
    const int bh = blockIdx.x;
    const int t = threadIdx.x;
    float* L = P + (size_t)bh * NN;
    __shared__ float red[256];
    float lmax = -1e30f;
    for (int n = t; n < NN; n += 256) lmax = fmaxf(lmax, L[n]);
    red[t] = lmax; __syncthreads();
    for (int s = 128; s > 0; s >>= 1) { if (t < s) red[t] = fmaxf(red[t], red[t+s]); __syncthreads(); }
    const float m = red[0]; __syncthreads();
    float z = 0.f;
    for (int n = t; n < NN; n += 256) z += expf(L[n] - m);
    red[t] = z; __syncthreads();
    for (int s = 128; s > 0; s >>= 1) { if (t < s) red[t] += red[t+s]; __syncthreads(); }
    const float Z = red[0];
    for (int n = t; n < NN; n += 256) L[n] = expf(L[n] - m) / Z;
}

// head-mean + rank-select top-k fused [validated R8..R11]
__global__ __launch_bounds__(256) void cls_meantopk(const float* __restrict__ P,
                                                    float* __restrict__ out_cls,
                                                    float* __restrict__ out_idx,
                                                    int* __restrict__ idxi)
{
    const int b = blockIdx.x;
    const int t = threadIdx.x;
    __shared__ float sv[576];
    for (int j = t; j < 576; j += 256) {
        float s = 0.f;
        #pragma unroll
        for (int h = 0; h < HH; ++h) s += P[((size_t)(b * HH + h)) * NN + 1 + j];
        const float v = s / 12.0f;
        sv[j] = v;
        out_cls[b * 576 + j] = v;
    }
    __syncthreads();
    for (int i = t; i < 576; i += 256) {
        const float vi = sv[i];
        int rank = 0;
        for (int j = 0; j < 576; ++j) {
            const float vj = sv[j];
            if (vj > vi || (vj == vi && j < i)) ++rank;
        }
        if (rank < LEFT) {
            out_idx[(size_t)b * LEFT + rank] = (float)i;
            idxi[(size_t)b * LEFT + rank] = i;
        }
    }
}

__global__ void write_index(const int* __restrict__ idxi, float* __restrict__ out_index)
{
    const int g4 = blockIdx.x * 256 + threadIdx.x;   // float4 index, 1,241,088 total
    const float v = (float)idxi[g4 / 192];           // 192 float4 per token row
    float4 o; o.x = v; o.y = v; o.z = v; o.w = v;
    ((float4*)out_index)[g4] = o;
}

// ---------------------------------------------------------------------------
extern "C" void kernel_launch(void* const* d_in, const int* in_sizes, int n_in,
                              void* d_out, int out_size, void* d_ws, size_t ws_size,
                              hipStream_t stream)
{
    const float* x      = (const float*)d_in[0];
    const float* qkv_w  = (const float*)d_in[1];
    const float* proj_w = (const float*)d_in[2];
    const float* proj_b = (const float*)d_in[3];
    float* out = (float*)d_out;

    // ws layout (bytes) — R5/R10-validated offsets
    char* base = (char*)d_ws;
    float*          kb    = (float*)(base + 0);                   // [192][577][64] f32
    unsigned short* xbh   = (unsigned short*)(base +  28360704);  // [9344][768] bf16
    unsigned short* qbh   = (unsigned short*)(base +  42713088);  // [192][608][64] bf16
    unsigned short* kbh   = (unsigned short*)(base +  57655296);  // [192][608][64] bf16
    unsigned short* Vt    = (unsigned short*)(base +  72597504);  // [192][64][608] bf16
    unsigned short* aobh  = (unsigned short*)(base +  87539712);  // [9344][768] bf16
    unsigned short* wqkv  = (unsigned short*)(base + 101892096);  // [2304][768] bf16
    unsigned short* wpb   = (unsigned short*)(base + 105431040);  // [768][768] bf16
    float*          qcls  = (float*)(base + 106610688);           // [16][768] f32
    float*          P     = (float*)(base + 106659840);           // [192][577] f32
    int*            idxi  = (int*)  (base + 107139840);           // [16][404] i32

    float* out_main  = out;                 // 7,090,176
    float* out_idx   = out + 7090176;       // 6,464
    float* out_index = out + 7096640;       // 4,964,352
    float* out_cls   = out + 12060992;      // 9,216

    convert3<<<9228, 256, 0, stream>>>(x, qkv_w, proj_w, xbh, wqkv, wpb);
    qcls_kernel<<<dim3(16, 3), 256, 0, stream>>>(x, qkv_w, qcls);
    k_gemm_fp32<<<dim3(73, 6), 256, 0, stream>>>(x, qkv_w, kb, kbh);
    qv_mfma<<<dim3(73, 12), 256, 0, stream>>>(xbh, wqkv, qbh, Vt);
    attn_mfma<<<BB * HH * NQT, 256, 0, stream>>>(qbh, kbh, Vt, aobh);
    proj_mfma<<<dim3(73, 6), 256, 0, stream>>>(aobh, wpb, proj_b, out_main);

    cls_logits<<<dim3(BB * HH, 3), 256, 0, stream>>>(qcls, kb, P);
    cls_softmax<<<BB * HH, 256, 0, stream>>>(P);
    cls_meantopk<<<BB, 256, 0, stream>>>(P, out_cls, out_idx, idxi);
    write_index<<<4848, 256, 0, stream>>>(idxi, out_index);
}

// Round 13
// 437.389 us; speedup vs baseline: 1.0599x; 1.0599x over previous
//
#include <hip/hip_runtime.h>
#include <math.h>

#define BB 16
#define NN 577
#define CC 768
#define HH 12
#define HD 64
#define MM (BB*NN)      // 9232
#define MPAD 9344       // 73*128
#define LEFT 404
#define NPAD 608        // padded token count (19 chunks of 32)
#define NQT 10          // ceil(577/64) q-tiles of 64

typedef __attribute__((ext_vector_type(8))) short short8v;   // 8 bf16
typedef __attribute__((ext_vector_type(4))) float f32x4;

__device__ __forceinline__ unsigned short f2bf(float f) {
    union { float f; unsigned int u; } v; v.f = f;
    unsigned int r = v.u + 0x7fffu + ((v.u >> 16) & 1u);   // RNE
    return (unsigned short)(r >> 16);
}

// ---------------------------------------------------------------------------
// fp32 K-GEMM v4 [best measured: 162 us, R8/R10]: 128x128 tile, 8x8
// conflict-free micro (4+4 offsets), single-buffer LDS + register prefetch,
// grid 73x6. Measured floor across 5 variants (162/167/191/231/307).
// Per-output ascending-k fmaf chain -> kb bit-exact (lottery draw preserved).
// ---------------------------------------------------------------------------
__global__ __launch_bounds__(256) void k_gemm_fp32(const float* __restrict__ X,
                                                   const float* __restrict__ W,
                                                   float* __restrict__ kb,
                                                   unsigned short* __restrict__ kbh)
{
    __shared__ float Xs[16][128];
    __shared__ float Ws[16][128];
    const int t  = threadIdx.x;
    const int tx = t & 15, ty = t >> 4;
    const int m0 = blockIdx.x * 128;
    const int n0 = 768 + blockIdx.y * 128;     // K columns of W
    const int sm = t & 127;
    const int sk = (t >> 7) * 8;

    float acc[8][8];
    #pragma unroll
    for (int i = 0; i < 8; ++i)
        #pragma unroll
        for (int j = 0; j < 8; ++j) acc[i][j] = 0.f;

    const int gm = m0 + sm;
    const float* px = X + (size_t)gm * CC + sk;
    const float* pw = W + (size_t)(n0 + sm) * CC + sk;

    float4 a0 = make_float4(0.f,0.f,0.f,0.f), a1 = a0, b0, b1;
    if (gm < MM) { a0 = *(const float4*)px; a1 = *(const float4*)(px + 4); }
    b0 = *(const float4*)pw; b1 = *(const float4*)(pw + 4);

    for (int kk = 0; kk < CC; kk += 16) {
        Xs[sk+0][sm] = a0.x; Xs[sk+1][sm] = a0.y; Xs[sk+2][sm] = a0.z; Xs[sk+3][sm] = a0.w;
        Xs[sk+4][sm] = a1.x; Xs[sk+5][sm] = a1.y; Xs[sk+6][sm] = a1.z; Xs[sk+7][sm] = a1.w;
        Ws[sk+0][sm] = b0.x; Ws[sk+1][sm] = b0.y; Ws[sk+2][sm] = b0.z; Ws[sk+3][sm] = b0.w;
        Ws[sk+4][sm] = b1.x; Ws[sk+5][sm] = b1.y; Ws[sk+6][sm] = b1.z; Ws[sk+7][sm] = b1.w;
        __syncthreads();
        if (kk + 16 < CC) {     // prefetch next K-tile into registers
            a0 = make_float4(0.f,0.f,0.f,0.f); a1 = a0;
            if (gm < MM) { a0 = *(const float4*)(px + kk + 16); a1 = *(const float4*)(px + kk + 20); }
            b0 = *(const float4*)(pw + kk + 16); b1 = *(const float4*)(pw + kk + 20);
        }
        #pragma unroll
        for (int k = 0; k < 16; ++k) {
            float a[8], bv[8];
            *(float4*)&a[0]  = *(const float4*)&Xs[k][ty*4];        // broadcast groups
            *(float4*)&a[4]  = *(const float4*)&Xs[k][64 + ty*4];
            *(float4*)&bv[0] = *(const float4*)&Ws[k][tx*4];        // 16B stride = 2-way (free)
            *(float4*)&bv[4] = *(const float4*)&Ws[k][64 + tx*4];
            #pragma unroll
            for (int i = 0; i < 8; ++i)
                #pragma unroll
                for (int j = 0; j < 8; ++j)
                    acc[i][j] = fmaf(a[i], bv[j], acc[i][j]);
        }
        __syncthreads();
    }
    #pragma unroll
    for (int i = 0; i < 8; ++i) {
        const int mrow = m0 + ((i < 4) ? (ty*4 + i) : (64 + ty*4 + i - 4));
        if (mrow >= MM) continue;
        const int b_ = mrow / NN;
        const int n_ = mrow - b_ * NN;
        #pragma unroll
        for (int j = 0; j < 8; ++j) {
            const int col = (n0 - 768) + ((j < 4) ? (tx*4 + j) : (64 + tx*4 + j - 4));
            const int h = col >> 6, d = col & 63;
            const float a = acc[i][j];
            kb [(((size_t)b_ * HH + h) * NN   + n_) * HD + d] = a;
            kbh[(((size_t)b_ * HH + h) * NPAD + n_) * HD + d] = f2bf(a);
        }
    }
}

// ---------------------------------------------------------------------------
// Exact fp32 q_cls (row 0 per (b,h)) — ascending-k fmaf chain [validated]
// ---------------------------------------------------------------------------
__global__ __launch_bounds__(256) void qcls_kernel(const float* __restrict__ X,
                                                   const float* __restrict__ W,
                                                   float* __restrict__ qcls)
{
    const int b = blockIdx.x;
    const int col = blockIdx.y * 256 + threadIdx.x;   // 0..767
    const float* xr = X + (size_t)b * NN * CC;        // CLS row
    const float* wr = W + (size_t)col * CC;
    float acc = 0.f;
    for (int k = 0; k < CC; ++k) acc = fmaf(xr[k], wr[k], acc);
    qcls[(size_t)b * CC + col] = acc;
}

// ---------------------------------------------------------------------------
// fp32 -> bf16 conversions (x, qkv_w, proj_w) in one launch [R5-validated]
// ---------------------------------------------------------------------------
#define N4X 1772544   // 9232*768/4
#define N4W 442368    // 2304*768/4
#define N4P 147456    // 768*768/4
__global__ __launch_bounds__(256) void convert3(const float* __restrict__ x,
                                                const float* __restrict__ wq,
                                                const float* __restrict__ wp,
                                                unsigned short* __restrict__ xb,
                                                unsigned short* __restrict__ wqb,
                                                unsigned short* __restrict__ wpb)
{
    int g = blockIdx.x * 256 + threadIdx.x;
    const float* src; unsigned short* dst;
    if (g < N4X)            { src = x;  dst = xb;  }
    else if (g < N4X + N4W) { g -= N4X; src = wq; dst = wqb; }
    else                    { g -= (N4X + N4W); src = wp; dst = wpb; }
    const float4 v = ((const float4*)src)[g];
    ushort4 o;
    o.x = f2bf(v.x); o.y = f2bf(v.y); o.z = f2bf(v.z); o.w = f2bf(v.w);
    ((ushort4*)dst)[g] = o;
}

// ---------------------------------------------------------------------------
// bf16 MFMA GEMM (C = A * B^T) for Q and V  [R10-validated, reg-staged]
// ---------------------------------------------------------------------------
__global__ __launch_bounds__(256) void qv_mfma(const unsigned short* __restrict__ xbh,
                                               const unsigned short* __restrict__ wqkv,
                                               unsigned short* __restrict__ qbh,
                                               unsigned short* __restrict__ Vt)
{
    __shared__ unsigned short As[128*32];
    __shared__ unsigned short Bs[128*32];
    const int t = threadIdx.x;
    const int w = t >> 6, l = t & 63;
    const int l15 = l & 15, lk = l >> 4;
    const int wm = w >> 1, wn = w & 1;
    const int m0 = blockIdx.x * 128;
    const int isV = blockIdx.y >= 6;
    const int nlocal0 = (isV ? (blockIdx.y - 6) : blockIdx.y) * 128;
    const int wrow0 = (isV ? 1536 : 0) + nlocal0;
    const int r0 = t >> 2, segp = t & 3;

    f32x4 acc[4][4];
    #pragma unroll
    for (int i = 0; i < 4; ++i)
        #pragma unroll
        for (int j = 0; j < 4; ++j) acc[i][j] = (f32x4){0.f,0.f,0.f,0.f};

    const unsigned short* ga = xbh  + (size_t)(m0 + r0) * CC + segp * 8;
    const unsigned short* gb = wqkv + (size_t)(wrow0 + r0) * CC + segp * 8;

    for (int kk = 0; kk < CC; kk += 32) {
        const short8v a0 = *(const short8v*)(ga + kk);
        const short8v a1 = *(const short8v*)(ga + kk + (size_t)64 * CC);
        const short8v b0 = *(const short8v*)(gb + kk);
        const short8v b1 = *(const short8v*)(gb + kk + (size_t)64 * CC);
        __syncthreads();
        *(short8v*)&As[(r0)      * 32 + segp*8] = a0;
        *(short8v*)&As[(64 + r0) * 32 + segp*8] = a1;
        *(short8v*)&Bs[(r0)      * 32 + segp*8] = b0;
        *(short8v*)&Bs[(64 + r0) * 32 + segp*8] = b1;
        __syncthreads();
        short8v fa[4], fb[4];
        #pragma unroll
        for (int i = 0; i < 4; ++i) fa[i] = *(const short8v*)&As[(wm*64 + i*16 + l15)*32 + lk*8];
        #pragma unroll
        for (int j = 0; j < 4; ++j) fb[j] = *(const short8v*)&Bs[(wn*64 + j*16 + l15)*32 + lk*8];
        #pragma unroll
        for (int i = 0; i < 4; ++i)
            #pragma unroll
            for (int j = 0; j < 4; ++j)
                acc[i][j] = __builtin_amdgcn_mfma_f32_16x16x32_bf16(fa[i], fb[j], acc[i][j], 0, 0, 0);
    }

    const int nb = nlocal0 + wn*64 + l15;
    #pragma unroll
    for (int i = 0; i < 4; ++i) {
        #pragma unroll
        for (int r = 0; r < 4; ++r) {
            const int m = m0 + wm*64 + i*16 + 4*lk + r;
            if (m >= MM) continue;
            const int b_ = m / NN, tok = m - b_ * NN;
            #pragma unroll
            for (int j = 0; j < 4; ++j) {
                const int nl = nb + j*16;
                const int h = nl >> 6, d = nl & 63;
                const unsigned short v = f2bf(acc[i][j][r]);
                if (isV) Vt [(((size_t)b_*HH + h)*HD + d)*NPAD + tok] = v;
                else     qbh[(((size_t)b_*HH + h)*NPAD + tok)*HD + d] = v;
            }
        }
    }
}

// proj GEMM: bf16 MFMA, out fp32 + bias   [R10-validated, reg-staged]
__global__ __launch_bounds__(256) void proj_mfma(const unsigned short* __restrict__ aobh,
                                                 const unsigned short* __restrict__ wpb,
                                                 const float* __restrict__ bias,
                                                 float* __restrict__ outp)
{
    __shared__ unsigned short As[128*32];
    __shared__ unsigned short Bs[128*32];
    const int t = threadIdx.x;
    const int w = t >> 6, l = t & 63;
    const int l15 = l & 15, lk = l >> 4;
    const int wm = w >> 1, wn = w & 1;
    const int m0 = blockIdx.x * 128;
    const int n0 = blockIdx.y * 128;
    const int r0 = t >> 2, segp = t & 3;

    f32x4 acc[4][4];
    #pragma unroll
    for (int i = 0; i < 4; ++i)
        #pragma unroll
        for (int j = 0; j < 4; ++j) acc[i][j] = (f32x4){0.f,0.f,0.f,0.f};

    const unsigned short* ga = aobh + (size_t)(m0 + r0) * CC + segp * 8;
    const unsigned short* gb = wpb  + (size_t)(n0 + r0) * CC + segp * 8;

    for (int kk = 0; kk < CC; kk += 32) {
        const short8v a0 = *(const short8v*)(ga + kk);
        const short8v a1 = *(const short8v*)(ga + kk + (size_t)64 * CC);
        const short8v b0 = *(const short8v*)(gb + kk);
        const short8v b1 = *(const short8v*)(gb + kk + (size_t)64 * CC);
        __syncthreads();
        *(short8v*)&As[(r0)      * 32 + segp*8] = a0;
        *(short8v*)&As[(64 + r0) * 32 + segp*8] = a1;
        *(short8v*)&Bs[(r0)      * 32 + segp*8] = b0;
        *(short8v*)&Bs[(64 + r0) * 32 + segp*8] = b1;
        __syncthreads();
        short8v fa[4], fb[4];
        #pragma unroll
        for (int i = 0; i < 4; ++i) fa[i] = *(const short8v*)&As[(wm*64 + i*16 + l15)*32 + lk*8];
        #pragma unroll
        for (int j = 0; j < 4; ++j) fb[j] = *(const short8v*)&Bs[(wn*64 + j*16 + l15)*32 + lk*8];
        #pragma unroll
        for (int i = 0; i < 4; ++i)
            #pragma unroll
            for (int j = 0; j < 4; ++j)
                acc[i][j] = __builtin_amdgcn_mfma_f32_16x16x32_bf16(fa[i], fb[j], acc[i][j], 0, 0, 0);
    }

    const int nb = n0 + wn*64 + l15;
    #pragma unroll
    for (int i = 0; i < 4; ++i) {
        #pragma unroll
        for (int r = 0; r < 4; ++r) {
            const int m = m0 + wm*64 + i*16 + 4*lk + r;
            if (m >= MM) continue;
            #pragma unroll
            for (int j = 0; j < 4; ++j) {
                const int n = nb + j*16;
                outp[(size_t)m * CC + n] = acc[i][j][r] + bias[n];
            }
        }
    }
}

// ---------------------------------------------------------------------------
// MFMA flash attention [validated R5/R10]: bf16 in (qbh/kbh/Vt), bf16 out
// ---------------------------------------------------------------------------
__global__ __launch_bounds__(256) void attn_mfma(const unsigned short* __restrict__ qbh,
                                                 const unsigned short* __restrict__ kbh,
                                                 const unsigned short* __restrict__ Vt,
                                                 unsigned short* __restrict__ aobh)
{
    __shared__ __align__(16) unsigned short plds[4][16][32];
    const int bid = blockIdx.x;
    const int bh  = bid / NQT;
    const int qt  = bid - bh * NQT;
    const int b   = bh / HH, h = bh - b * HH;
    const int t   = threadIdx.x;
    const int w   = t >> 6, l = t & 63;
    const int l15 = l & 15, lg = l >> 4;

    short8v aq0, aq1;
    {
        int qrow = qt*64 + w*16 + l15; if (qrow > 576) qrow = 576;
        const unsigned short* qp = qbh + ((size_t)bh * NPAD + qrow) * HD + lg*8;
        aq0 = *(const short8v*)(qp);
        aq1 = *(const short8v*)(qp + 32);
    }

    f32x4 O0 = {0.f,0.f,0.f,0.f}, O1 = O0, O2 = O0, O3 = O0;
    float mr[4] = {-1e30f,-1e30f,-1e30f,-1e30f};
    float lr[4] = {0.f,0.f,0.f,0.f};

    const unsigned short* kwb = kbh + (size_t)bh * NPAD * HD + (size_t)l15 * HD + lg*8;
    const unsigned short* vwb = Vt  + (size_t)bh * HD * NPAD + (size_t)l15 * NPAD + lg*8;

    for (int c = 0; c < 19; ++c) {
        const int n0 = c * 32;
        const unsigned short* kp = kwb + (size_t)n0 * HD;
        short8v bk00 = *(const short8v*)(kp);
        short8v bk01 = *(const short8v*)(kp + 32);
        short8v bk10 = *(const short8v*)(kp + 16*HD);
        short8v bk11 = *(const short8v*)(kp + 16*HD + 32);
        f32x4 s0 = {0.f,0.f,0.f,0.f}, s1 = {0.f,0.f,0.f,0.f};
        s0 = __builtin_amdgcn_mfma_f32_16x16x32_bf16(aq0, bk00, s0, 0, 0, 0);
        s0 = __builtin_amdgcn_mfma_f32_16x16x32_bf16(aq1, bk01, s0, 0, 0, 0);
        s1 = __builtin_amdgcn_mfma_f32_16x16x32_bf16(aq0, bk10, s1, 0, 0, 0);
        s1 = __builtin_amdgcn_mfma_f32_16x16x32_bf16(aq1, bk11, s1, 0, 0, 0);

        const int nc0 = n0 + l15;
        float p0[4], p1[4], al[4];
        #pragma unroll
        for (int r = 0; r < 4; ++r) {
            float a0 = (nc0      <= 576) ? s0[r] * 0.125f : -1e30f;
            float a1 = (nc0 + 16 <= 576) ? s1[r] * 0.125f : -1e30f;
            float tm = fmaxf(a0, a1);
            tm = fmaxf(tm, __shfl_xor(tm, 1, 64));
            tm = fmaxf(tm, __shfl_xor(tm, 2, 64));
            tm = fmaxf(tm, __shfl_xor(tm, 4, 64));
            tm = fmaxf(tm, __shfl_xor(tm, 8, 64));
            const float mn = fmaxf(mr[r], tm);
            al[r] = __expf(mr[r] - mn);
            mr[r] = mn;
            p0[r] = __expf(a0 - mn);
            p1[r] = __expf(a1 - mn);
            float ps = p0[r] + p1[r];
            ps += __shfl_xor(ps, 1, 64);
            ps += __shfl_xor(ps, 2, 64);
            ps += __shfl_xor(ps, 4, 64);
            ps += __shfl_xor(ps, 8, 64);
            lr[r] = lr[r] * al[r] + ps;
        }
        #pragma unroll
        for (int r = 0; r < 4; ++r) {
            O0[r] *= al[r]; O1[r] *= al[r]; O2[r] *= al[r]; O3[r] *= al[r];
        }
        #pragma unroll
        for (int r = 0; r < 4; ++r) {
            plds[w][lg*4 + r][l15]      = f2bf(p0[r]);
            plds[w][lg*4 + r][16 + l15] = f2bf(p1[r]);
        }
        asm volatile("s_waitcnt lgkmcnt(0)" ::: "memory");
        short8v pa = *(const short8v*)&plds[w][l15][lg*8];
        const unsigned short* vp = vwb + n0;
        short8v v0 = *(const short8v*)(vp);
        short8v v1 = *(const short8v*)(vp + 16*NPAD);
        short8v v2 = *(const short8v*)(vp + 32*NPAD);
        short8v v3 = *(const short8v*)(vp + 48*NPAD);
        O0 = __builtin_amdgcn_mfma_f32_16x16x32_bf16(pa, v0, O0, 0, 0, 0);
        O1 = __builtin_amdgcn_mfma_f32_16x16x32_bf16(pa, v1, O1, 0, 0, 0);
        O2 = __builtin_amdgcn_mfma_f32_16x16x32_bf16(pa, v2, O2, 0, 0, 0);
        O3 = __builtin_amdgcn_mfma_f32_16x16x32_bf16(pa, v3, O3, 0, 0, 0);
    }

    #pragma unroll
    for (int r = 0; r < 4; ++r) {
        const float inv = 1.f / lr[r];
        const int row = qt*64 + w*16 + lg*4 + r;
        if (row <= 576) {
            unsigned short* op = aobh + ((size_t)b * NN + row) * CC + h*HD + l15;
            op[0]  = f2bf(O0[r] * inv);
            op[16] = f2bf(O1[r] * inv);
            op[32] = f2bf(O2[r] * inv);
            op[48] = f2bf(O3[r] * inv);
        }
    }
}

// ---------------------------------------------------------------------------
// CLS path — bit-identical math to the passing R3..R12 draw [R9 split]
// ---------------------------------------------------------------------------
__global__ __launch_bounds__(256) void cls_logits(const float* __restrict__ qcls,
                                                  const float* __restrict__ kb,
                                                  float* __restrict__ P)
{
    const int bh = blockIdx.x;
    const int t = threadIdx.x;
    __shared__ float q[64];
    if (t < 64) q[t] = qcls[(size_t)bh * 64 + t];
    __syncthreads();
    const int n = blockIdx.y * 193 + t;
    if (t < 193 && n < NN) {
        const float* kr = kb + ((size_t)bh * NN + n) * HD;
        float acc = 0.f;
        #pragma unroll
        for (int d = 0; d < 64; ++d) acc = fmaf(q[d], kr[d], acc);
        P[(size_t)bh * NN + n] = acc * 0.125f;
    }
}

__global__ __launch_bounds__(256) void cls_softmax(float* __restrict__ P)
{
    const int bh = blockIdx.x;
    const int t = threadIdx.x;
    float* L = P + (size_t)bh * NN;
    __shared__ float red[256];
    float lmax = -1e30f;
    for (int n = t; n < NN; n += 256) lmax = fmaxf(lmax, L[n]);
    red[t] = lmax; __syncthreads();
    for (int s = 128; s > 0; s >>= 1) { if (t < s) red[t] = fmaxf(red[t], red[t+s]); __syncthreads(); }
    const float m = red[0]; __syncthreads();
    float z = 0.f;
    for (int n = t; n < NN; n += 256) z += expf(L[n] - m);
    red[t] = z; __syncthreads();
    for (int s = 128; s > 0; s >>= 1) { if (t < s) red[t] += red[t+s]; __syncthreads(); }
    const float Z = red[0];
    for (int n = t; n < NN; n += 256) L[n] = expf(L[n] - m) / Z;
}

// head-mean + rank-select top-k fused [validated R8..R12]
__global__ __launch_bounds__(256) void cls_meantopk(const float* __restrict__ P,
                                                    float* __restrict__ out_cls,
                                                    float* __restrict__ out_idx,
                                                    int* __restrict__ idxi)
{
    const int b = blockIdx.x;
    const int t = threadIdx.x;
    __shared__ float sv[576];
    for (int j = t; j < 576; j += 256) {
        float s = 0.f;
        #pragma unroll
        for (int h = 0; h < HH; ++h) s += P[((size_t)(b * HH + h)) * NN + 1 + j];
        const float v = s / 12.0f;
        sv[j] = v;
        out_cls[b * 576 + j] = v;
    }
    __syncthreads();
    for (int i = t; i < 576; i += 256) {
        const float vi = sv[i];
        int rank = 0;
        for (int j = 0; j < 576; ++j) {
            const float vj = sv[j];
            if (vj > vi || (vj == vi && j < i)) ++rank;
        }
        if (rank < LEFT) {
            out_idx[(size_t)b * LEFT + rank] = (float)i;
            idxi[(size_t)b * LEFT + rank] = i;
        }
    }
}

__global__ void write_index(const int* __restrict__ idxi, float* __restrict__ out_index)
{
    const int g4 = blockIdx.x * 256 + threadIdx.x;   // float4 index, 1,241,088 total
    const float v = (float)idxi[g4 / 192];           // 192 float4 per token row
    float4 o; o.x = v; o.y = v; o.z = v; o.w = v;
    ((float4*)out_index)[g4] = o;
}

// ---------------------------------------------------------------------------
extern "C" void kernel_launch(void* const* d_in, const int* in_sizes, int n_in,
                              void* d_out, int out_size, void* d_ws, size_t ws_size,
                              hipStream_t stream)
{
    const float* x      = (const float*)d_in[0];
    const float* qkv_w  = (const float*)d_in[1];
    const float* proj_w = (const float*)d_in[2];
    const float* proj_b = (const float*)d_in[3];
    float* out = (float*)d_out;

    // ws layout (bytes) — R5/R10-validated offsets
    char* base = (char*)d_ws;
    float*          kb    = (float*)(base + 0);                   // [192][577][64] f32
    unsigned short* xbh   = (unsigned short*)(base +  28360704);  // [9344][768] bf16
    unsigned short* qbh   = (unsigned short*)(base +  42713088);  // [192][608][64] bf16
    unsigned short* kbh   = (unsigned short*)(base +  57655296);  // [192][608][64] bf16
    unsigned short* Vt    = (unsigned short*)(base +  72597504);  // [192][64][608] bf16
    unsigned short* aobh  = (unsigned short*)(base +  87539712);  // [9344][768] bf16
    unsigned short* wqkv  = (unsigned short*)(base + 101892096);  // [2304][768] bf16
    unsigned short* wpb   = (unsigned short*)(base + 105431040);  // [768][768] bf16
    float*          qcls  = (float*)(base + 106610688);           // [16][768] f32
    float*          P     = (float*)(base + 106659840);           // [192][577] f32
    int*            idxi  = (int*)  (base + 107139840);           // [16][404] i32

    float* out_main  = out;                 // 7,090,176
    float* out_idx   = out + 7090176;       // 6,464
    float* out_index = out + 7096640;       // 4,964,352
    float* out_cls   = out + 12060992;      // 9,216

    convert3<<<9228, 256, 0, stream>>>(x, qkv_w, proj_w, xbh, wqkv, wpb);
    qcls_kernel<<<dim3(16, 3), 256, 0, stream>>>(x, qkv_w, qcls);
    k_gemm_fp32<<<dim3(73, 6), 256, 0, stream>>>(x, qkv_w, kb, kbh);
    qv_mfma<<<dim3(73, 12), 256, 0, stream>>>(xbh, wqkv, qbh, Vt);
    attn_mfma<<<BB * HH * NQT, 256, 0, stream>>>(qbh, kbh, Vt, aobh);
    proj_mfma<<<dim3(73, 6), 256, 0, stream>>>(aobh, wpb, proj_b, out_main);

    cls_logits<<<dim3(BB * HH, 3), 256, 0, stream>>>(qcls, kb, P);
    cls_softmax<<<BB * HH, 256, 0, stream>>>(P);
    cls_meantopk<<<BB, 256, 0, stream>>>(P, out_cls, out_idx, idxi);
    write_index<<<4848, 256, 0, stream>>>(idxi, out_index);
}